// Round 7
// baseline (307.559 us; speedup 1.0000x reference)
//
#include <hip/hip_runtime.h>
#include <hip/hip_bf16.h>
#include <math.h>

#define DIMC   1024
#define NHEADS 16
#define HDIM   64
#define BATCH  2
#define SEQ    2048
#define SCALE  0.125f

typedef unsigned short u16;
typedef __attribute__((ext_vector_type(8))) short bf16x8;   // 8 bf16 = 4 VGPRs
typedef __attribute__((ext_vector_type(4))) float f32x4;

// [B][H][N][D] per tensor, element count
#define BHND ((size_t)BATCH * NHEADS * SEQ * HDIM)   // 4,194,304
#define MROWS ((size_t)BATCH * SEQ)                  // 4096

__device__ __forceinline__ u16 f2bf(float x) {
    __hip_bfloat16 h = __float2bfloat16(x);
    return *reinterpret_cast<u16*>(&h);
}
__device__ __forceinline__ float bf2f(u16 x) {
    unsigned int u = ((unsigned int)x) << 16;
    return __uint_as_float(u);
}
__device__ __forceinline__ void gload_lds16(const u16* g, u16* l) {
    __builtin_amdgcn_global_load_lds(
        (const __attribute__((address_space(1))) unsigned int*)g,
        (__attribute__((address_space(3))) unsigned int*)l, 16, 0, 0);
}

// ---------------------------------------------------------------------------
// Prepass 1: elementwise split fp32 -> bf16 hi + lo  (hi+lo ~= x to 2^-17)
// ---------------------------------------------------------------------------
__global__ __launch_bounds__(256) void splita_kernel(
    const float* __restrict__ in, u16* __restrict__ hi, u16* __restrict__ lo)
{
    int i = (blockIdx.x * 256 + threadIdx.x) * 8;
    float4 a = *(const float4*)&in[i];
    float4 b = *(const float4*)&in[i + 4];
    float v[8] = {a.x, a.y, a.z, a.w, b.x, b.y, b.z, b.w};
    bf16x8 vh, vl;
    #pragma unroll
    for (int j = 0; j < 8; ++j) {
        u16 h = f2bf(v[j]);
        vh[j] = (short)h;
        vl[j] = (short)f2bf(v[j] - bf2f(h));
    }
    *(bf16x8*)&hi[i] = vh;
    *(bf16x8*)&lo[i] = vl;
}

// ---------------------------------------------------------------------------
// Prepass 2: W [K][N] fp32 -> transposed split bf16  Thi/Tlo [N][K]
// ---------------------------------------------------------------------------
__global__ __launch_bounds__(256) void splitw_kernel(
    const float* __restrict__ W, u16* __restrict__ Thi, u16* __restrict__ Tlo,
    int K, int N)
{
    __shared__ float Ws[64][65];
    const int kb  = blockIdx.x * 64;
    const int nb  = blockIdx.y * 64;
    const int tid = threadIdx.x;
    const int jr  = (tid & 15) * 4;
    const int ir  = tid >> 4;
    #pragma unroll
    for (int it = 0; it < 4; ++it) {
        int i = ir + it * 16;
        *(float4*)&Ws[i][jr] = *(const float4*)&W[(size_t)(kb + i) * N + nb + jr];
    }
    __syncthreads();
    const int n  = tid >> 2;
    const int k0 = (tid & 3) * 16;
    bf16x8 h0, h1, l0, l1;
    #pragma unroll
    for (int kk = 0; kk < 8; ++kk) {
        float x = Ws[k0 + kk][n];
        u16 h = f2bf(x);
        h0[kk] = (short)h; l0[kk] = (short)f2bf(x - bf2f(h));
        float y = Ws[k0 + 8 + kk][n];
        u16 h2 = f2bf(y);
        h1[kk] = (short)h2; l1[kk] = (short)f2bf(y - bf2f(h2));
    }
    size_t off = (size_t)(nb + n) * K + kb + k0;
    *(bf16x8*)&Thi[off]     = h0;
    *(bf16x8*)&Thi[off + 8] = h1;
    *(bf16x8*)&Tlo[off]     = l0;
    *(bf16x8*)&Tlo[off + 8] = l1;
}

// ---------------------------------------------------------------------------
// Split-bf16 MFMA GEMM (validated round 6). 128x128 tile, BK=32,
// 4 waves x (64x64), global_load_lds staging, 3 MFMAs per fragment pair.
// MODE 0: scatter bf16 q(*SCALE)/k [B][H][N][D], v^T [B][H][D][N]
// MODE 1: + bias, fp32 store to out[M][N]
// ---------------------------------------------------------------------------
template <int MODE>
__global__ __launch_bounds__(256) void gemm_split_kernel(
    const u16* __restrict__ Ahi, const u16* __restrict__ Alo,
    const u16* __restrict__ Bhi, const u16* __restrict__ Blo,
    const float* __restrict__ bias,
    float* __restrict__ outf, u16* __restrict__ outb,
    int M, int N, int K)
{
    __shared__ __align__(16) u16 lds[4][128 * 32];   // Ahi, Alo, BhiT, BloT

    const int bm   = blockIdx.y * 128;
    const int bn   = blockIdx.x * 128;
    const int tid  = threadIdx.x;
    const int wid  = tid >> 6;
    const int lane = tid & 63;
    const int lo   = lane & 15;
    const int g4   = lane >> 4;
    const int wr   = wid >> 1, wc = wid & 1;

    const int mrow = lane >> 2;
    const int ks8  = (lane & 3) * 8;
    const u16* g0;
    if      (wid == 0) g0 = Ahi + (size_t)(bm + mrow) * K + ks8;
    else if (wid == 1) g0 = Alo + (size_t)(bm + mrow) * K + ks8;
    else if (wid == 2) g0 = Bhi + (size_t)(bn + mrow) * K + ks8;
    else               g0 = Blo + (size_t)(bn + mrow) * K + ks8;
    u16* lbase = &lds[wid][0];

    f32x4 acc[4][4] = {};

    for (int k0 = 0; k0 < K; k0 += 32) {
        const u16* g = g0 + k0;
        #pragma unroll
        for (int s = 0; s < 8; ++s)
            gload_lds16(g + (size_t)s * 16 * K, lbase + s * 512);
        __syncthreads();

        bf16x8 bh[4], bl[4];
        #pragma unroll
        for (int ni = 0; ni < 4; ++ni) {
            int row = wc * 64 + ni * 16 + lo;
            bh[ni] = *(const bf16x8*)&lds[2][row * 32 + g4 * 8];
            bl[ni] = *(const bf16x8*)&lds[3][row * 32 + g4 * 8];
        }
        #pragma unroll
        for (int mi = 0; mi < 4; ++mi) {
            int row = wr * 64 + mi * 16 + lo;
            bf16x8 ah = *(const bf16x8*)&lds[0][row * 32 + g4 * 8];
            bf16x8 al = *(const bf16x8*)&lds[1][row * 32 + g4 * 8];
            #pragma unroll
            for (int ni = 0; ni < 4; ++ni) {
                acc[mi][ni] = __builtin_amdgcn_mfma_f32_16x16x32_bf16(ah, bh[ni], acc[mi][ni], 0, 0, 0);
                acc[mi][ni] = __builtin_amdgcn_mfma_f32_16x16x32_bf16(ah, bl[ni], acc[mi][ni], 0, 0, 0);
                acc[mi][ni] = __builtin_amdgcn_mfma_f32_16x16x32_bf16(al, bh[ni], acc[mi][ni], 0, 0, 0);
            }
        }
        __syncthreads();
    }

    if (MODE == 0) {
        #pragma unroll
        for (int mi = 0; mi < 4; ++mi) {
            int m0 = bm + wr * 64 + mi * 16 + 4 * g4;
            #pragma unroll
            for (int ni = 0; ni < 4; ++ni) {
                int n0    = bn + wc * 64 + ni * 16;
                int which = n0 >> 10;
                int head  = (n0 & 1023) >> 6;
                int d     = (n0 & 63) + lo;
                if (which == 0) {
                    #pragma unroll
                    for (int r = 0; r < 4; ++r) {
                        int m = m0 + r, b = m >> 11, seq = m & 2047;
                        outb[(((size_t)b * NHEADS + head) * SEQ + seq) * HDIM + d] =
                            f2bf(acc[mi][ni][r] * SCALE);
                    }
                } else if (which == 1) {
                    #pragma unroll
                    for (int r = 0; r < 4; ++r) {
                        int m = m0 + r, b = m >> 11, seq = m & 2047;
                        outb[BHND + (((size_t)b * NHEADS + head) * SEQ + seq) * HDIM + d] =
                            f2bf(acc[mi][ni][r]);
                    }
                } else {
                    int b = m0 >> 11, seq0 = m0 & 2047;
                    ushort4 o;
                    o.x = f2bf(acc[mi][ni][0]); o.y = f2bf(acc[mi][ni][1]);
                    o.z = f2bf(acc[mi][ni][2]); o.w = f2bf(acc[mi][ni][3]);
                    *(ushort4*)&outb[2 * BHND +
                        (((size_t)b * NHEADS + head) * HDIM + d) * SEQ + seq0] = o;
                }
            }
        }
    } else {
        #pragma unroll
        for (int ni = 0; ni < 4; ++ni) {
            int col = bn + wc * 64 + ni * 16 + lo;
            float bv = bias[col];
            #pragma unroll
            for (int mi = 0; mi < 4; ++mi) {
                int m0 = bm + wr * 64 + mi * 16 + 4 * g4;
                #pragma unroll
                for (int r = 0; r < 4; ++r)
                    outf[(size_t)(m0 + r) * N + col] = acc[mi][ni][r] + bv;
            }
        }
    }
}

// ---------------------------------------------------------------------------
// MFMA flash attention, KVBLK=64 (was 32): halves softmax shuffle/rescale
// cost per key; MFMA per key unchanged. Bit-exact skip-rescale (corr==1.0
// exactly when no row max grew). K and V^T LDS tiles XOR-swizzled
// (128B rows raw = 16-way bank conflict). Split-bf16 O epilogue.
// ---------------------------------------------------------------------------
__global__ __launch_bounds__(256) void attn_mfma_kernel(
    const u16* __restrict__ qb, const u16* __restrict__ kb,
    const u16* __restrict__ vtb, const float* __restrict__ mask,
    u16* __restrict__ ohi, u16* __restrict__ olo)
{
    __shared__ __align__(16) u16 Ks[64 * 64];       // [key][d] swizzled
    __shared__ __align__(16) u16 Vt[64 * 64];       // [d][key] swizzled
    __shared__ __align__(16) u16 Plds[4][16 * 72];
    __shared__ float Ms[64];

    const int bid  = blockIdx.x;          // 1024 = B*H*(SEQ/64)
    const int qt   = bid & 31;
    const int h    = (bid >> 5) & 15;
    const int b    = bid >> 9;
    const int tid  = threadIdx.x;
    const int wid  = tid >> 6;
    const int lane = tid & 63;
    const int lo   = lane & 15;
    const int g    = lane >> 4;

    const size_t bh = (size_t)b * NHEADS + h;
    const int qbase = qt * 64 + wid * 16;

    // Q A-frags: row = qbase+lo, kdim = ks*32 + 8g + j
    const u16* qrowp = qb + (bh * SEQ + qbase + lo) * HDIM + 8 * g;
    const bf16x8 aq0 = *(const bf16x8*)(qrowp);
    const bf16x8 aq1 = *(const bf16x8*)(qrowp + 32);

    // staging: 64x64 tiles, thread -> row = tid>>2, two 8-elem slots
    const int srow  = tid >> 2;
    const int scol  = (tid & 3) * 16;
    const int swz   = (srow & 7) << 3;
    const int idx0  = srow * 64 + (scol ^ swz);
    const int idx1  = srow * 64 + ((scol + 8) ^ swz);
    const u16* kgp  = kb  + (bh * SEQ  + srow) * HDIM + scol;   // + k0*HDIM
    const u16* vgp  = vtb + (bh * HDIM + srow) * SEQ  + scol;   // + k0

    f32x4 acc[4] = {};
    float mrun[4], lrun[4];
    #pragma unroll
    for (int r = 0; r < 4; ++r) { mrun[r] = -1e30f; lrun[r] = 0.f; }

    u16* pw = &Plds[wid][0];

    for (int k0 = 0; k0 < SEQ; k0 += 64) {
        __syncthreads();
        *(bf16x8*)&Ks[idx0] = *(const bf16x8*)(kgp + (size_t)k0 * HDIM);
        *(bf16x8*)&Ks[idx1] = *(const bf16x8*)(kgp + (size_t)k0 * HDIM + 8);
        *(bf16x8*)&Vt[idx0] = *(const bf16x8*)(vgp + k0);
        *(bf16x8*)&Vt[idx1] = *(const bf16x8*)(vgp + k0 + 8);
        if (tid < 64) Ms[tid] = mask[b * SEQ + k0 + tid];
        __syncthreads();

        // QK^T: S[16q x 64key], 8 MFMAs (q pre-scaled by SCALE)
        f32x4 s[4];
        #pragma unroll
        for (int kt = 0; kt < 4; ++kt) {
            int key  = lo + 16 * kt;
            int kbse = key * 64;
            int ksw  = (key & 7) << 3;
            f32x4 t = {};
            t = __builtin_amdgcn_mfma_f32_16x16x32_bf16(aq0, *(const bf16x8*)&Ks[kbse + ((8 * g) ^ ksw)], t, 0, 0, 0);
            t = __builtin_amdgcn_mfma_f32_16x16x32_bf16(aq1, *(const bf16x8*)&Ks[kbse + ((32 + 8 * g) ^ ksw)], t, 0, 0, 0);
            s[kt] = t;
        }

        // online softmax, UNMASKED denominator; skip-rescale is bit-exact
        float p0v[4], p1v[4], p2v[4], p3v[4];
        #pragma unroll
        for (int r = 0; r < 4; ++r) {
            float rm = fmaxf(fmaxf(s[0][r], s[1][r]), fmaxf(s[2][r], s[3][r]));
            rm = fmaxf(rm, __shfl_xor(rm, 1));
            rm = fmaxf(rm, __shfl_xor(rm, 2));
            rm = fmaxf(rm, __shfl_xor(rm, 4));
            rm = fmaxf(rm, __shfl_xor(rm, 8));
            if (!__all(rm <= mrun[r])) {      // corr == 1.0 exactly when skipped
                float mnew = fmaxf(mrun[r], rm);
                float corr = __expf(mrun[r] - mnew);
                mrun[r] = mnew;
                lrun[r] *= corr;
                #pragma unroll
                for (int dt = 0; dt < 4; ++dt) acc[dt][r] *= corr;
            }
            float p0 = __expf(s[0][r] - mrun[r]);
            float p1 = __expf(s[1][r] - mrun[r]);
            float p2 = __expf(s[2][r] - mrun[r]);
            float p3 = __expf(s[3][r] - mrun[r]);
            float ps = (p0 + p1) + (p2 + p3);
            ps += __shfl_xor(ps, 1);
            ps += __shfl_xor(ps, 2);
            ps += __shfl_xor(ps, 4);
            ps += __shfl_xor(ps, 8);
            lrun[r] += ps;
            p0v[r] = p0; p1v[r] = p1; p2v[r] = p2; p3v[r] = p3;
        }

        // masked numerator -> P in LDS (A-frag layout for PV)
        const float mv0 = Ms[lo], mv1 = Ms[lo + 16], mv2 = Ms[lo + 32], mv3 = Ms[lo + 48];
        #pragma unroll
        for (int r = 0; r < 4; ++r) {
            int prow = (4 * g + r) * 72;
            pw[prow + lo]      = f2bf(p0v[r] * mv0);
            pw[prow + lo + 16] = f2bf(p1v[r] * mv1);
            pw[prow + lo + 32] = f2bf(p2v[r] * mv2);
            pw[prow + lo + 48] = f2bf(p3v[r] * mv3);
        }

        // PV: O += P[16,64] @ V[64,64]  (same-wave DS ops are in-order)
        const bf16x8 pa0 = *(const bf16x8*)&pw[lo * 72 + 8 * g];
        const bf16x8 pa1 = *(const bf16x8*)&pw[lo * 72 + 8 * g + 32];
        #pragma unroll
        for (int dt = 0; dt < 4; ++dt) {
            int vbse = (lo + 16 * dt) * 64;
            int vsw  = (lo & 7) << 3;
            acc[dt] = __builtin_amdgcn_mfma_f32_16x16x32_bf16(pa0, *(const bf16x8*)&Vt[vbse + ((8 * g) ^ vsw)], acc[dt], 0, 0, 0);
            acc[dt] = __builtin_amdgcn_mfma_f32_16x16x32_bf16(pa1, *(const bf16x8*)&Vt[vbse + ((32 + 8 * g) ^ vsw)], acc[dt], 0, 0, 0);
        }
    }

    // epilogue: split bf16 O for the split proj GEMM
    #pragma unroll
    for (int r = 0; r < 4; ++r) {
        float inv = 1.f / lrun[r];
        size_t row = (size_t)b * SEQ + qbase + 4 * g + r;
        u16* dh = ohi + row * DIMC + h * HDIM + lo;
        u16* dl = olo + row * DIMC + h * HDIM + lo;
        #pragma unroll
        for (int dt = 0; dt < 4; ++dt) {
            float o = acc[dt][r] * inv;
            u16 hv = f2bf(o);
            dh[16 * dt] = hv;
            dl[16 * dt] = f2bf(o - bf2f(hv));
        }
    }
}

__global__ void mask_sqrt_kernel(const float* __restrict__ mask,
                                 float* __restrict__ out, int n)
{
    int i = blockIdx.x * 256 + threadIdx.x;
    if (i < n) out[i] = sqrtf(mask[i]);
}

// ---------------------------------------------------------------------------
extern "C" void kernel_launch(void* const* d_in, const int* in_sizes, int n_in,
                              void* d_out, int out_size, void* d_ws, size_t ws_size,
                              hipStream_t stream)
{
    const float* h      = (const float*)d_in[0];   // [2,2048,1024]
    const float* mask   = (const float*)d_in[1];   // [2,2048]
    const float* w_qkv  = (const float*)d_in[2];   // [1024,3072]
    const float* w_proj = (const float*)d_in[3];   // [1024,1024]
    const float* b_proj = (const float*)d_in[4];   // [1024]
    float* out = (float*)d_out;

    // ws layout (u16 units), ~59 MB total
    u16* w    = (u16*)d_ws;
    u16* qkv  = w;                                  // 3*BHND
    u16* wqh  = qkv + 3 * BHND;                     // 3072*1024
    u16* wql  = wqh + (size_t)3072 * 1024;
    u16* wph  = wql + (size_t)3072 * 1024;          // 1024*1024
    u16* wpl  = wph + (size_t)1024 * 1024;
    u16* ahi  = wpl + (size_t)1024 * 1024;          // 4096*1024 (h split; later O split)
    u16* alo  = ahi + MROWS * DIMC;

    // prepasses: split h; split+transpose weights
    splita_kernel<<<(MROWS * DIMC) / (256 * 8), 256, 0, stream>>>(h, ahi, alo);
    splitw_kernel<<<dim3(16, 48), 256, 0, stream>>>(w_qkv, wqh, wql, DIMC, 3 * DIMC);
    splitw_kernel<<<dim3(16, 16), 256, 0, stream>>>(w_proj, wph, wpl, DIMC, DIMC);

    // 1) qkv projection (split MFMA) -> bf16 q(scaled)/k [B][H][N][D], v^T [B][H][D][N]
    gemm_split_kernel<0><<<dim3(24, 32), 256, 0, stream>>>(
        ahi, alo, wqh, wql, nullptr, nullptr, qkv, MROWS, 3 * DIMC, DIMC);

    // 2) MFMA flash attention (KVBLK=64) -> split O over the dead h-split buffers
    attn_mfma_kernel<<<BATCH * NHEADS * (SEQ / 64), 256, 0, stream>>>(
        qkv, qkv + BHND, qkv + 2 * BHND, mask, ahi, alo);

    // 3) output projection + bias (split MFMA, fp32 out)
    gemm_split_kernel<1><<<dim3(8, 32), 256, 0, stream>>>(
        ahi, alo, wph, wpl, b_proj, out, nullptr, MROWS, DIMC, DIMC);

    // 4) new_mask = sqrt(mask)
    mask_sqrt_kernel<<<(BATCH * SEQ + 255) / 256, 256, 0, stream>>>(
        mask, out + MROWS * DIMC, BATCH * SEQ);
}